// Round 7
// baseline (127.503 us; speedup 1.0000x reference)
//
#include <hip/hip_runtime.h>

#define EPS 1e-7f
#define T_DIM 2048
#define TP1   2049
#define H_DIM 8
#define B_DIM 8
#define SP    2304   // padded xT row length (bf16 el): [2048,2304) zero -> overshoot-safe
#define NFRAG 148    // A-fragment table: b0 = fb*16 - 256, fb in [0,148) -> b0 in [-256,2096]
#define FB_OFF 256

typedef short v8s __attribute__((ext_vector_type(8)));
typedef float v4f __attribute__((ext_vector_type(4)));

static __device__ __forceinline__ unsigned short f2bf(float f) {
  union { float f; unsigned u; } v; v.f = f;
  unsigned r = v.u + 0x7fffu + ((v.u >> 16) & 1u);  // RTNE
  return (unsigned short)(r >> 16);
}

#define J1_BLOCKS 296    // fragA: 8*148 frags * 64 lanes / 256
#define J2_BLOCKS 264    // transpose + head-H norm: 8 * 33

// Fused prep: [J1] MFMA A-fragment table; [J2] x -> bf16 transpose AND head-H
// output (single l2norm of xp) from the same x read.
__global__ __launch_bounds__(256) void prep(const float* __restrict__ x,
                                            const float* __restrict__ W,
                                            unsigned short* __restrict__ fragA,
                                            unsigned short* __restrict__ xT,
                                            float* __restrict__ out) {
  __shared__ float tile[64][65];
  int bid = blockIdx.x;
  if (bid < J1_BLOCKS) {
    // fragA[((h*NFRAG+fb)*64+lane)*8]: A[m=lm][k=quad*8+j] = k_h[b0+lm-8q-j], b0=fb*16-256
    int tid = bid * 256 + threadIdx.x;
    int blk = tid >> 6, lane = tid & 63;
    int h = blk / NFRAG, fb = blk - h * NFRAG;
    int b0 = fb * 16 - FB_OFF;
    int lm = lane & 15, quad = lane >> 4;
    v8s frag;
    #pragma unroll
    for (int j = 0; j < 8; ++j) {
      int d = b0 + lm - 8 * quad - j;
      float v = 0.0f;
      if (d >= 0 && d < T_DIM) v = __expf(W[d * H_DIM + h]);
      else if (d == T_DIM) v = 1.0f;
      frag[j] = (short)f2bf(v);
    }
    *(v8s*)(fragA + (size_t)tid * 8) = frag;
    return;
  }
  bid -= J1_BLOCKS;
  {
    int b = bid / 33, st = bid % 33;
    int tid = threadIdx.x;
    if (st == 32) {  // zero pad s in [2048,2304) for this b
      v8s z = {0, 0, 0, 0, 0, 0, 0, 0};
      #pragma unroll
      for (int i = 0; i < 8; ++i) {
        int idx = tid * 8 + i;          // 0..2047
        int row = idx >> 5, c32 = idx & 31;
        *(v8s*)(xT + ((size_t)b * 64 + row) * SP + T_DIM + c32 * 8) = z;
      }
      if (b == 0) {  // head-H t=2048 rows are zero vectors -> zero output
        for (int i = tid; i < 512; i += 256)
          __builtin_nontemporal_store(0.0f,
            &out[(((size_t)(H_DIM * B_DIM + (i >> 6)) * TP1 + T_DIM) << 6) + (i & 63)]);
      }
      return;
    }
    int s0 = st * 64;
    int c = tid & 63, r4 = tid >> 6;
    #pragma unroll
    for (int i = 0; i < 16; ++i) {
      int sl = r4 * 16 + i;
      tile[sl][c] = x[((size_t)b * T_DIM + (s0 + sl)) * 64 + c];
    }
    __syncthreads();
    #pragma unroll
    for (int i = 0; i < 16; ++i) {
      int dd = r4 * 16 + i;
      xT[((size_t)b * 64 + dd) * SP + s0 + c] = f2bf(tile[c][dd]);
    }
    // head-H (single l2norm of x rows) from the LDS tile
    #pragma unroll
    for (int i = 0; i < 16; ++i) {
      int row = r4 * 16 + i;
      float v = tile[row][c];
      float ss = v * v;
      ss += __shfl_xor(ss, 1);  ss += __shfl_xor(ss, 2);
      ss += __shfl_xor(ss, 4);  ss += __shfl_xor(ss, 8);
      ss += __shfl_xor(ss, 16); ss += __shfl_xor(ss, 32);
      float inv = 1.0f / (sqrtf(ss) + EPS);
      __builtin_nontemporal_store(v * inv,
          &out[(((size_t)(H_DIM * B_DIM + b) * TP1 + (s0 + row)) << 6) + c]);
    }
  }
}

// Toeplitz GEMM, M=64 rows/wave, shift-reuse A, depth-3 pipeline, BRANCHLESS:
// steps rounded up to x4; padded steps read zero A-frags (exact 0 contribution)
// and valid zero-padded B. No clamps, no mid-loop exits -> compiler can keep
// 18 loads in flight and wait only on 3-phase-old loads.
// Slot algebra: frag(mt,p) lives in slot (mt-2p)&7; phase period 4 => slot
// pattern repeats per iteration (2*4 % 8 == 0), all indices compile-time.
__global__ __launch_bounds__(256) void toeplitz_mm(const unsigned short* __restrict__ fragA,
                                                   const unsigned short* __restrict__ xT,
                                                   float* __restrict__ out) {
  const int lane = threadIdx.x & 63;
  const int w    = threadIdx.x >> 6;
  const int lm   = lane & 15;
  const int quad = lane >> 4;

  const int bi   = blockIdx.x;
  const int rank = (bi < 256) ? bi : (bi < 512 ? 767 - bi : bi);  // anti-gradient pairing
  const int j    = rank * 4 + w;
  const int strip = 32 - (j >> 6);       // 0..32; strip 32 covers row t=2048 (masked)
  const int combo = j & 63;              // 4 consecutive jobs share b -> L1 B-sharing
  const int h = combo & 7, b = combo >> 3;
  const int tw = strip * 64;

  const unsigned short* fA = fragA + ((size_t)h * NFRAG * 64 + lane) * 8;
  const unsigned short* xb = xT + ((size_t)b * 64 + lm) * SP + 8 * quad;

  const int nsteps = 2 * strip + 2;      // covers s0 = 0..tw+32 (last real step)
  const int niter  = (nsteps + 3) >> 2;  // x4-rounded; extra steps are exact zeros
  const int fbase  = (tw + FB_OFF) >> 4;

  v4f acc[4][4] = {};   // rows tw+16*mt+4*quad+r, cols 16*nt+lm
  v8s As[8];            // slot (mt-2p)&7 holds frag(mt, step p)
  v8s Bs[4][4];         // 4-phase rotation, prefetch distance 3

  // Prologue: A slots for steps 0..2, B buffers for steps 0..2.
  {
    const v8s* ba = (const v8s*)(fA + (size_t)fbase * 512);
    As[0] = ba[0];    As[1] = ba[64];   As[2] = ba[128]; As[3] = ba[192];
    As[4] = ba[-256]; As[5] = ba[-192]; As[6] = ba[-128]; As[7] = ba[-64];
  }
  #pragma unroll
  for (int p = 0; p < 3; ++p) {
    const unsigned short* _p = xb + 32 * p;
    Bs[p][0] = *(const v8s*)(_p);
    Bs[p][1] = *(const v8s*)(_p + 16 * SP);
    Bs[p][2] = *(const v8s*)(_p + 32 * SP);
    Bs[p][3] = *(const v8s*)(_p + 48 * SP);
  }

  const v8s* pa = (const v8s*)(fA + (size_t)(fbase - 6) * 512);  // frag(0, p+3) chain
  const unsigned short* pb = xb + 96;                            // B(s=96) chain

#define PHASE(PH) {                                                           \
    { const v8s* _bq = Bs[(PH) & 3];                                          \
      _Pragma("unroll")                                                       \
      for (int nt = 0; nt < 4; ++nt) {                                        \
        acc[0][nt] = __builtin_amdgcn_mfma_f32_16x16x32_bf16(As[(0 - 2*(PH)) & 7], _bq[nt], acc[0][nt], 0, 0, 0); \
        acc[1][nt] = __builtin_amdgcn_mfma_f32_16x16x32_bf16(As[(1 - 2*(PH)) & 7], _bq[nt], acc[1][nt], 0, 0, 0); \
        acc[2][nt] = __builtin_amdgcn_mfma_f32_16x16x32_bf16(As[(2 - 2*(PH)) & 7], _bq[nt], acc[2][nt], 0, 0, 0); \
        acc[3][nt] = __builtin_amdgcn_mfma_f32_16x16x32_bf16(As[(3 - 2*(PH)) & 7], _bq[nt], acc[3][nt], 0, 0, 0); \
      } }                                                                     \
    As[(0 - 2*(PH) - 6) & 7] = pa[0];                                         \
    As[(1 - 2*(PH) - 6) & 7] = pa[64];                                        \
    pa -= 128;                                                                \
    { v8s* _d = Bs[((PH) + 3) & 3];                                           \
      _d[0] = *(const v8s*)(pb);                                              \
      _d[1] = *(const v8s*)(pb + 16 * SP);                                    \
      _d[2] = *(const v8s*)(pb + 32 * SP);                                    \
      _d[3] = *(const v8s*)(pb + 48 * SP);                                    \
      pb += 32; } }

  #pragma unroll 1
  for (int it = 0; it < niter; ++it) {
    PHASE(0) PHASE(1) PHASE(2) PHASE(3)
  }
#undef PHASE

  // Epilogue: double l2-norm over dd (softmax Z cancels up to eps ~3e-7).
  // C/D layout: col = lane&15, row = quad*4 + reg. Mask t<=2048 (strip 32).
  #pragma unroll
  for (int mt = 0; mt < 4; ++mt) {
    #pragma unroll
    for (int r = 0; r < 4; ++r) {
      float ss = 0.0f;
      #pragma unroll
      for (int nt = 0; nt < 4; ++nt) { float a = acc[mt][nt][r]; ss += a * a; }
      ss += __shfl_xor(ss, 1);
      ss += __shfl_xor(ss, 2);
      ss += __shfl_xor(ss, 4);
      ss += __shfl_xor(ss, 8);
      int t = tw + 16 * mt + 4 * quad + r;
      if (t <= T_DIM) {
        float n1 = sqrtf(ss);
        float u  = n1 / (n1 + EPS);
        float inv = 1.0f / ((n1 + EPS) * (u + EPS));
        float* op = out + (((size_t)(h * B_DIM + b) * TP1 + t) << 6) + lm;
        #pragma unroll
        for (int nt = 0; nt < 4; ++nt)
          __builtin_nontemporal_store(acc[mt][nt][r] * inv, op + 16 * nt);
      }
    }
  }
}

extern "C" void kernel_launch(void* const* d_in, const int* in_sizes, int n_in,
                              void* d_out, int out_size, void* d_ws, size_t ws_size,
                              hipStream_t stream) {
  const float* x = (const float*)d_in[0];   // [8, 2048, 64] fp32
  const float* W = (const float*)d_in[1];   // [2048, 8] fp32
  float* out = (float*)d_out;               // [9, 8, 2049, 64] fp32

  unsigned short* xT    = (unsigned short*)d_ws;                    // 8*64*2304*2 = 2,359,296 B
  unsigned short* fragA = (unsigned short*)((char*)d_ws + 2359296); // 8*148*64*8*2 = 1,212,416 B

  hipLaunchKernelGGL(prep, dim3(J1_BLOCKS + J2_BLOCKS), dim3(256), 0, stream,
                     x, W, fragA, xT, out);
  hipLaunchKernelGGL(toeplitz_mm, dim3(528), dim3(256), 0, stream, fragA, xT, out);
}